// Round 1
// baseline (245182.910 us; speedup 1.0000x reference)
//
#include <hip/hip_runtime.h>

// Reservoir (Echo State Network) forward:
//   for t in 1..4095: s(t) = tanh(W s(t-1) + W_in inp[t] + W_fb outp[t-1]) + noise[t]
//   out = concat( s(4095) @ W_out  (16),  [ s(4095) (2048) | inputs[4095] (64) | outputs[4094] (16) ] )
//
// Strategy: single persistent kernel, W entirely in VGPRs (64 KB/CU), flag-based
// device-wide sync per step (monotonic per-wg counters, release/acquire at agent scope).

#define NRES 2048
#define NIN  64
#define NOUT 16
#define TT   4096
#define GWG  256   // workgroups (1 per CU)
#define BTH  512   // threads per wg (8 waves); one wave per owned row
#define ROWS_PER_WG 8      // NRES / GWG
#define KPL  32            // W cols per lane: NRES / 64

__global__ void init_ws(float* statebuf, unsigned* flags) {
    int i = blockIdx.x * blockDim.x + threadIdx.x;
    if (i < 2 * NRES) statebuf[i] = 0.0f;
    if (i < GWG)      flags[i] = 0u;
}

__launch_bounds__(BTH, 2)
__global__ void reservoir_run(const float* __restrict__ inputs,
                              const float* __restrict__ outputs,
                              const float* __restrict__ noise,
                              const float* __restrict__ w,
                              const float* __restrict__ w_in,
                              const float* __restrict__ w_feedb,
                              float* statebuf, unsigned* flags)
{
    const int wg   = blockIdx.x;      // 0..255
    const int tid  = threadIdx.x;     // 0..511
    const int wave = tid >> 6;        // 0..7
    const int lane = tid & 63;
    const int row  = wg * ROWS_PER_WG + wave;   // global state row this wave owns

    // ---- load this wave's W row into registers (cols: lane + 64*k) ----
    const float* wrow = w + (size_t)row * NRES;
    float wreg[KPL];
#pragma unroll
    for (int k = 0; k < KPL; ++k) wreg[k] = wrow[lane + 64 * k];
    const float wi = w_in[row * NIN + lane];                       // one per lane
    const float wf = (lane < NOUT) ? w_feedb[row * NOUT + lane] : 0.0f;

    __shared__ float s_state[NRES];

    for (int t = 1; t < TT; ++t) {
        const float* sbuf = statebuf + ((t - 1) & 1) * NRES;
        float*       dbuf = statebuf + (t & 1) * NRES;
        const unsigned target = 8u * (unsigned)(t - 1);

        // ---- wait until every wg has published state(t-1) ----
        if (tid < GWG) {
            while (__hip_atomic_load(&flags[tid], __ATOMIC_RELAXED,
                                     __HIP_MEMORY_SCOPE_AGENT) < target) {}
        }
        __syncthreads();
        __threadfence();   // acquire: invalidate stale cached state lines

        // ---- stage state(t-1) into LDS (coherent loads) ----
#pragma unroll
        for (int j = 0; j < NRES / BTH; ++j) {
            int idx = tid + j * BTH;
            s_state[idx] = __hip_atomic_load(&sbuf[idx], __ATOMIC_RELAXED,
                                             __HIP_MEMORY_SCOPE_AGENT);
        }
        __syncthreads();

        // ---- row dot products ----
        float acc = 0.0f;
#pragma unroll
        for (int k = 0; k < KPL; ++k)
            acc = fmaf(wreg[k], s_state[lane + 64 * k], acc);
        acc = fmaf(wi, inputs[t * NIN + lane], acc);
        if (lane < NOUT)
            acc = fmaf(wf, outputs[(t - 1) * NOUT + lane], acc);

        // ---- wave-wide butterfly reduce (64 lanes) ----
#pragma unroll
        for (int off = 32; off; off >>= 1) acc += __shfl_xor(acc, off, 64);

        // ---- publish new state row ----
        if (lane == 0) {
            float ns = tanhf(acc) + noise[(size_t)t * NRES + row];
            __hip_atomic_store(&dbuf[row], ns, __ATOMIC_RELAXED,
                               __HIP_MEMORY_SCOPE_AGENT);
            __hip_atomic_fetch_add(&flags[wg], 1u, __ATOMIC_RELEASE,
                                   __HIP_MEMORY_SCOPE_AGENT);
        }
        // next iteration's poll + __syncthreads keeps s_state safe from overwrite
    }
}

__global__ void epilogue(const float* __restrict__ statebuf,
                         const float* __restrict__ inputs,
                         const float* __restrict__ outputs,
                         const float* __restrict__ w_out,
                         float* __restrict__ out)
{
    const float* s = statebuf + ((TT - 1) & 1) * NRES;   // state(4095) lives in buf 1
    const int tid  = threadIdx.x;   // 1024 threads = 16 waves
    const int wave = tid >> 6;
    const int lane = tid & 63;

    // out_activation[wave] = sum_r s[r] * w_out[r*16 + wave]
    float acc = 0.0f;
#pragma unroll
    for (int k = 0; k < NRES / 64; ++k) {
        int r = lane + 64 * k;
        acc = fmaf(s[r], w_out[r * NOUT + wave], acc);
    }
#pragma unroll
    for (int off = 32; off; off >>= 1) acc += __shfl_xor(acc, off, 64);
    if (lane == 0) out[wave] = acc;

    // final_state = [ s (2048) | inputs[T-1] (64) | outputs[T-2] (16) ]
    for (int i = tid; i < NRES; i += 1024) out[NOUT + i] = s[i];
    if (tid < NIN)  out[NOUT + NRES + tid]       = inputs[(TT - 1) * NIN + tid];
    if (tid < NOUT) out[NOUT + NRES + NIN + tid] = outputs[(TT - 2) * NOUT + tid];
}

extern "C" void kernel_launch(void* const* d_in, const int* in_sizes, int n_in,
                              void* d_out, int out_size, void* d_ws, size_t ws_size,
                              hipStream_t stream) {
    const float* inputs  = (const float*)d_in[0];   // (4096, 64)
    const float* outputs = (const float*)d_in[1];   // (4096, 16)
    const float* noise   = (const float*)d_in[2];   // (4096, 2048)
    const float* w       = (const float*)d_in[3];   // (2048, 2048)
    const float* w_in    = (const float*)d_in[4];   // (2048, 64)
    const float* w_feedb = (const float*)d_in[5];   // (2048, 16)
    const float* w_out   = (const float*)d_in[6];   // (2048, 16)
    float* out = (float*)d_out;                     // 16 + 2128 = 2144 floats

    float*    statebuf = (float*)d_ws;                                  // 2*2048 f32
    unsigned* flags    = (unsigned*)((char*)d_ws + 2 * NRES * sizeof(float));  // 256 u32

    init_ws<<<dim3((2 * NRES + 511) / 512), dim3(512), 0, stream>>>(statebuf, flags);
    reservoir_run<<<dim3(GWG), dim3(BTH), 0, stream>>>(inputs, outputs, noise,
                                                       w, w_in, w_feedb,
                                                       statebuf, flags);
    epilogue<<<dim3(1), dim3(1024), 0, stream>>>(statebuf, inputs, outputs, w_out, out);
}

// Round 3
// 132496.716 us; speedup vs baseline: 1.8505x; 1.8505x over previous
//
#include <hip/hip_runtime.h>

// Reservoir (Echo State Network) forward:
//   for t in 1..4095: s(t) = tanh(W s(t-1) + W_in inp[t] + W_fb outp[t-1]) + noise[t]
//   out = concat( s(4095) @ W_out (16), [ s(4095) | inputs[4095] | outputs[4094] ] )
//
// R3 = R2 with the compile fix (__threadfence instead of __hip_atomic_fence):
//     64 wgs x 1024 thr (32 rows/wg, 2 rows/wave, W in VGPRs: 64 regs/thread).
//     Padded per-wg flags (128B apart), one polling lane per flag + s_sleep backoff.
//     Prefetch read-only step data before the wait to hide its latency.

#define NRES 2048
#define NIN  64
#define NOUT 16
#define TT   4096
#define GWG  64            // workgroups
#define BTH  1024          // threads per wg (16 waves)
#define ROWS_PER_WG 32     // NRES / GWG
#define KPL  32            // W cols per lane: NRES / 64
#define FPAD 32            // flag padding in u32 (128 B per flag line)

__global__ void init_ws(float* statebuf, unsigned* flags) {
    int i = blockIdx.x * blockDim.x + threadIdx.x;
    if (i < 2 * NRES)      statebuf[i] = 0.0f;
    if (i < GWG * FPAD)    flags[i] = 0u;
}

__launch_bounds__(BTH, 4)   // cap at 128 VGPR so 16 waves co-reside (1 wg/CU)
__global__ void reservoir_run(const float* __restrict__ inputs,
                              const float* __restrict__ outputs,
                              const float* __restrict__ noise,
                              const float* __restrict__ w,
                              const float* __restrict__ w_in,
                              const float* __restrict__ w_feedb,
                              float* statebuf, unsigned* flags)
{
    const int wg   = blockIdx.x;      // 0..63
    const int tid  = threadIdx.x;     // 0..1023
    const int wave = tid >> 6;        // 0..15
    const int lane = tid & 63;
    const int row0 = wg * ROWS_PER_WG + wave * 2;   // this wave owns rows row0, row0+1

    // ---- W rows resident in VGPRs: 2 rows x 32 cols/lane = 64 regs ----
    const float* wr0 = w + (size_t)row0 * NRES;
    const float* wr1 = w + (size_t)(row0 + 1) * NRES;
    float wreg0[KPL], wreg1[KPL];
#pragma unroll
    for (int k = 0; k < KPL; ++k) {
        wreg0[k] = wr0[lane + 64 * k];
        wreg1[k] = wr1[lane + 64 * k];
    }
    const float wi0 = w_in[row0 * NIN + lane];
    const float wi1 = w_in[(row0 + 1) * NIN + lane];
    const float wf0 = (lane < NOUT) ? w_feedb[row0 * NOUT + lane] : 0.0f;
    const float wf1 = (lane < NOUT) ? w_feedb[(row0 + 1) * NOUT + lane] : 0.0f;

    __shared__ float s_state[NRES];

    for (int t = 1; t < TT; ++t) {
        const float* sbuf = statebuf + ((t - 1) & 1) * NRES;
        float*       dbuf = statebuf + (t & 1) * NRES;

        // ---- prefetch step-t read-only data (latency hides under the wait) ----
        const float inp      = inputs[t * NIN + lane];
        const float prev_out = (lane < NOUT) ? outputs[(t - 1) * NOUT + lane] : 0.0f;
        const float nz       = (lane < 2) ? noise[(size_t)t * NRES + row0 + lane] : 0.0f;
        float acc0 = fmaf(wf0, prev_out, wi0 * inp);
        float acc1 = fmaf(wf1, prev_out, wi1 * inp);

        // ---- wait: all wgs have published state(t-1) ----
        if (tid < GWG) {
            while (__hip_atomic_load(&flags[tid * FPAD], __ATOMIC_RELAXED,
                                     __HIP_MEMORY_SCOPE_AGENT) < (unsigned)(t - 1)) {
                __builtin_amdgcn_s_sleep(1);
            }
        }
        __syncthreads();
        __threadfence();   // acquire: order flag observation before state loads

        // ---- stage state(t-1) into LDS (coalesced agent loads) ----
#pragma unroll
        for (int j = 0; j < NRES / BTH; ++j) {       // 2 iterations
            int idx = tid + j * BTH;
            s_state[idx] = __hip_atomic_load(&sbuf[idx], __ATOMIC_RELAXED,
                                             __HIP_MEMORY_SCOPE_AGENT);
        }
        __syncthreads();

        // ---- two row dot-products (shared s reads, 2-way LDS alias = free) ----
#pragma unroll
        for (int k = 0; k < KPL; ++k) {
            float sv = s_state[lane + 64 * k];
            acc0 = fmaf(wreg0[k], sv, acc0);
            acc1 = fmaf(wreg1[k], sv, acc1);
        }
#pragma unroll
        for (int off = 32; off; off >>= 1) {
            acc0 += __shfl_xor(acc0, off, 64);
            acc1 += __shfl_xor(acc1, off, 64);
        }

        // ---- publish: lanes 0/1 do tanh+noise+store in parallel ----
        if (lane < 2) {
            float a  = (lane == 0) ? acc0 : acc1;
            float ns = tanhf(a) + nz;
            __hip_atomic_store(&dbuf[row0 + lane], ns, __ATOMIC_RELAXED,
                               __HIP_MEMORY_SCOPE_AGENT);
        }
        __threadfence();                 // release: drain state stores
        __syncthreads();                 // all waves of this wg done
        if (tid == 0)
            __hip_atomic_store(&flags[wg * FPAD], (unsigned)t, __ATOMIC_RELEASE,
                               __HIP_MEMORY_SCOPE_AGENT);
    }
}

__global__ void epilogue(const float* __restrict__ statebuf,
                         const float* __restrict__ inputs,
                         const float* __restrict__ outputs,
                         const float* __restrict__ w_out,
                         float* __restrict__ out)
{
    const float* s = statebuf + ((TT - 1) & 1) * NRES;   // state(4095) in buf 1
    const int tid  = threadIdx.x;   // 1024 threads = 16 waves
    const int wave = tid >> 6;
    const int lane = tid & 63;

    // out_activation[wave] = sum_r s[r] * w_out[r*16 + wave]
    float acc = 0.0f;
#pragma unroll
    for (int k = 0; k < NRES / 64; ++k) {
        int r = lane + 64 * k;
        acc = fmaf(s[r], w_out[r * NOUT + wave], acc);
    }
#pragma unroll
    for (int off = 32; off; off >>= 1) acc += __shfl_xor(acc, off, 64);
    if (lane == 0) out[wave] = acc;

    // final_state = [ s (2048) | inputs[T-1] (64) | outputs[T-2] (16) ]
    for (int i = tid; i < NRES; i += 1024) out[NOUT + i] = s[i];
    if (tid < NIN)  out[NOUT + NRES + tid]       = inputs[(TT - 1) * NIN + tid];
    if (tid < NOUT) out[NOUT + NRES + NIN + tid] = outputs[(TT - 2) * NOUT + tid];
}

extern "C" void kernel_launch(void* const* d_in, const int* in_sizes, int n_in,
                              void* d_out, int out_size, void* d_ws, size_t ws_size,
                              hipStream_t stream) {
    const float* inputs  = (const float*)d_in[0];   // (4096, 64)
    const float* outputs = (const float*)d_in[1];   // (4096, 16)
    const float* noise   = (const float*)d_in[2];   // (4096, 2048)
    const float* w       = (const float*)d_in[3];   // (2048, 2048)
    const float* w_in    = (const float*)d_in[4];   // (2048, 64)
    const float* w_feedb = (const float*)d_in[5];   // (2048, 16)
    const float* w_out   = (const float*)d_in[6];   // (2048, 16)
    float* out = (float*)d_out;                     // 16 + 2128 floats

    float*    statebuf = (float*)d_ws;                                       // 2*2048 f32
    unsigned* flags    = (unsigned*)((char*)d_ws + 2 * NRES * sizeof(float)); // 64*32 u32

    init_ws<<<dim3(16), dim3(256), 0, stream>>>(statebuf, flags);
    reservoir_run<<<dim3(GWG), dim3(BTH), 0, stream>>>(inputs, outputs, noise,
                                                       w, w_in, w_feedb,
                                                       statebuf, flags);
    epilogue<<<dim3(1), dim3(1024), 0, stream>>>(statebuf, inputs, outputs, w_out, out);
}

// Round 4
// 16354.750 us; speedup vs baseline: 14.9915x; 8.1014x over previous
//
#include <hip/hip_runtime.h>

// Reservoir forward, R4: self-synchronizing epoch-tagged state exchange.
//   Each state element is a u64: (epoch << 32) | f32 bits, written/read with
//   relaxed agent-scope 64-bit atomics. Readers poll until epoch matches.
//   -> no flags, no fences, no release/acquire cache maintenance.
//   W pinned in VGPRs via opaque asm (64 regs/thread), 64 wgs x 1024 thr.

typedef unsigned long long u64;

#define NRES 2048
#define NIN  64
#define NOUT 16
#define TT   4096
#define GWG  64            // workgroups (1 per CU)
#define BTH  1024          // threads per wg (16 waves)
#define ROWS_PER_WG 32     // NRES / GWG
#define KPL  32            // W cols per lane: NRES / 64

__global__ void init_ws(u64* statebuf) {
    int i = blockIdx.x * blockDim.x + threadIdx.x;
    if (i < NRES)            statebuf[i] = 0ull;                     // buf0: epoch 0, value 0.0f
    else if (i < 2 * NRES)   statebuf[i] = 0xFFFFFFFF00000000ull;    // buf1: invalid epoch
}

__launch_bounds__(BTH, 4)   // cap 128 VGPR -> 16 waves co-resident, 1 wg/CU
__global__ void reservoir_run(const float* __restrict__ inputs,
                              const float* __restrict__ outputs,
                              const float* __restrict__ noise,
                              const float* __restrict__ w,
                              const float* __restrict__ w_in,
                              const float* __restrict__ w_feedb,
                              u64* statebuf)
{
    const int wg   = blockIdx.x;      // 0..63
    const int tid  = threadIdx.x;     // 0..1023
    const int wave = tid >> 6;        // 0..15
    const int lane = tid & 63;
    const int row0 = wg * ROWS_PER_WG + wave * 2;   // wave owns rows row0, row0+1

    // ---- W rows into VGPRs: 2 rows x 32 cols/lane = 64 regs/thread ----
    const float* wr0 = w + (size_t)row0 * NRES;
    const float* wr1 = w + (size_t)(row0 + 1) * NRES;
    float wreg0[KPL], wreg1[KPL];
#pragma unroll
    for (int k = 0; k < KPL; ++k) {
        wreg0[k] = wr0[lane + 64 * k];
        wreg1[k] = wr1[lane + 64 * k];
    }
    // Opaque pin: values become asm outputs -> not rematerializable, must stay
    // in VGPRs (or visibly spill). This is what keeps W out of the L2 path.
#pragma unroll
    for (int k = 0; k < KPL; ++k) {
        asm volatile("" : "+v"(wreg0[k]), "+v"(wreg1[k]));
    }
    const float wi0 = w_in[row0 * NIN + lane];
    const float wi1 = w_in[(row0 + 1) * NIN + lane];
    const float wf0 = (lane < NOUT) ? w_feedb[row0 * NOUT + lane] : 0.0f;
    const float wf1 = (lane < NOUT) ? w_feedb[(row0 + 1) * NOUT + lane] : 0.0f;

    __shared__ float s_state[2][NRES];   // parity-indexed by epoch of contents

    for (int t = 1; t < TT; ++t) {
        const u64* sbuf = statebuf + ((t - 1) & 1) * NRES;
        u64*       dbuf = statebuf + (t & 1) * NRES;
        float*     sl   = s_state[(t - 1) & 1];
        const unsigned want = (unsigned)(t - 1);

        // ---- prefetch step-t read-only data (hides under the poll) ----
        const float inp      = inputs[t * NIN + lane];
        const float prev_out = (lane < NOUT) ? outputs[(t - 1) * NOUT + lane] : 0.0f;
        const float nz       = (lane < 2) ? noise[(size_t)t * NRES + row0 + lane] : 0.0f;
        float acc0 = fmaf(wf0, prev_out, wi0 * inp);
        float acc1 = fmaf(wf1, prev_out, wi1 * inp);

        // ---- poll-stage state(t-1): the epoch tag IS the sync ----
        u64 p0, p1;
        do {
            p0 = __hip_atomic_load(&sbuf[tid], __ATOMIC_RELAXED,
                                   __HIP_MEMORY_SCOPE_AGENT);
        } while ((unsigned)(p0 >> 32) != want);
        do {
            p1 = __hip_atomic_load(&sbuf[tid + BTH], __ATOMIC_RELAXED,
                                   __HIP_MEMORY_SCOPE_AGENT);
        } while ((unsigned)(p1 >> 32) != want);
        sl[tid]       = __uint_as_float((unsigned)p0);
        sl[tid + BTH] = __uint_as_float((unsigned)p1);
        __syncthreads();   // the only barrier per step (LDS parity dbuf covers WAR)

        // ---- two row dot-products from VGPR-resident W ----
#pragma unroll
        for (int k = 0; k < KPL; ++k) {
            float sv = sl[lane + 64 * k];
            acc0 = fmaf(wreg0[k], sv, acc0);
            acc1 = fmaf(wreg1[k], sv, acc1);
        }
#pragma unroll
        for (int off = 32; off; off >>= 1) {
            acc0 += __shfl_xor(acc0, off, 64);
            acc1 += __shfl_xor(acc1, off, 64);
        }

        // ---- publish: epoch-tagged 64-bit atomic store, no fence ----
        if (lane < 2) {
            float a  = (lane == 0) ? acc0 : acc1;
            float ns = tanhf(a) + nz;
            u64 packed = ((u64)(unsigned)t << 32) | (u64)__float_as_uint(ns);
            __hip_atomic_store(&dbuf[row0 + lane], packed, __ATOMIC_RELAXED,
                               __HIP_MEMORY_SCOPE_AGENT);
        }
    }
}

__global__ void epilogue(const u64* __restrict__ statebuf,
                         const float* __restrict__ inputs,
                         const float* __restrict__ outputs,
                         const float* __restrict__ w_out,
                         float* __restrict__ out)
{
    const u64* sb = statebuf + ((TT - 1) & 1) * NRES;   // state(4095) in buf 1
    const int tid  = threadIdx.x;   // 1024 threads = 16 waves
    const int wave = tid >> 6;
    const int lane = tid & 63;

    // out_activation[wave] = sum_r s[r] * w_out[r*16 + wave]
    float acc = 0.0f;
#pragma unroll
    for (int k = 0; k < NRES / 64; ++k) {
        int r = lane + 64 * k;
        acc = fmaf(__uint_as_float((unsigned)sb[r]), w_out[r * NOUT + wave], acc);
    }
#pragma unroll
    for (int off = 32; off; off >>= 1) acc += __shfl_xor(acc, off, 64);
    if (lane == 0) out[wave] = acc;

    // final_state = [ s (2048) | inputs[T-1] (64) | outputs[T-2] (16) ]
    for (int i = tid; i < NRES; i += 1024)
        out[NOUT + i] = __uint_as_float((unsigned)sb[i]);
    if (tid < NIN)  out[NOUT + NRES + tid]       = inputs[(TT - 1) * NIN + tid];
    if (tid < NOUT) out[NOUT + NRES + NIN + tid] = outputs[(TT - 2) * NOUT + tid];
}

extern "C" void kernel_launch(void* const* d_in, const int* in_sizes, int n_in,
                              void* d_out, int out_size, void* d_ws, size_t ws_size,
                              hipStream_t stream) {
    const float* inputs  = (const float*)d_in[0];   // (4096, 64)
    const float* outputs = (const float*)d_in[1];   // (4096, 16)
    const float* noise   = (const float*)d_in[2];   // (4096, 2048)
    const float* w       = (const float*)d_in[3];   // (2048, 2048)
    const float* w_in    = (const float*)d_in[4];   // (2048, 64)
    const float* w_feedb = (const float*)d_in[5];   // (2048, 16)
    const float* w_out   = (const float*)d_in[6];   // (2048, 16)
    float* out = (float*)d_out;                     // 16 + 2128 floats

    u64* statebuf = (u64*)d_ws;                     // 2 * 2048 u64 = 32 KB

    init_ws<<<dim3(8), dim3(512), 0, stream>>>(statebuf);
    reservoir_run<<<dim3(GWG), dim3(BTH), 0, stream>>>(inputs, outputs, noise,
                                                       w, w_in, w_feedb, statebuf);
    epilogue<<<dim3(1), dim3(1024), 0, stream>>>(statebuf, inputs, outputs, w_out, out);
}